// Round 5
// baseline (30.088 us; speedup 1.0000x reference)
//
#include <hip/hip_runtime.h>
#include <math.h>

#define NF 50
#define REC 52   // per-block record: 50 z + s + pad
#define NBLK 1024
#define GRP_PER_BLK 32   // 512 threads = 32 groups of 16 lanes
#define LOG2E 1.44269504f

// All-lanes sum within each 16-lane DPP row via rotate butterfly.
__device__ __forceinline__ float row16_allsum(float v) {
    float t;
    t = __int_as_float(__builtin_amdgcn_update_dpp(0, __float_as_int(v), 0x121, 0xF, 0xF, true)); v += t; // row_ror:1
    t = __int_as_float(__builtin_amdgcn_update_dpp(0, __float_as_int(v), 0x122, 0xF, 0xF, true)); v += t; // row_ror:2
    t = __int_as_float(__builtin_amdgcn_update_dpp(0, __float_as_int(v), 0x124, 0xF, 0xF, true)); v += t; // row_ror:4
    t = __int_as_float(__builtin_amdgcn_update_dpp(0, __float_as_int(v), 0x128, 0xF, 0xF, true)); v += t; // row_ror:8
    return v;
}

// Per-lane partial of sum_f w_f / (e^{2 qW x_f} + 1)  (the r-part of w*tanh).
__device__ __forceinline__ float row_partial(float2 a, float2 b, float c2,
                                             float wA0, float wA1, float wB0, float wB1) {
    float r0 = __builtin_amdgcn_rcpf(__builtin_amdgcn_exp2f(c2 * a.x) + 1.f);
    float r1 = __builtin_amdgcn_rcpf(__builtin_amdgcn_exp2f(c2 * a.y) + 1.f);
    float r2 = __builtin_amdgcn_rcpf(__builtin_amdgcn_exp2f(c2 * b.x) + 1.f);
    float r3 = __builtin_amdgcn_rcpf(__builtin_amdgcn_exp2f(c2 * b.y) + 1.f);
    return fmaf(wA0, r0, fmaf(wA1, r1, fmaf(wB0, r2, wB1 * r3)));
}

#define LOAD4(baseRow, A0,B0,A1,B1,A2,B2,A3,B3) do {                                  \
    const float2* q0_ = (const float2*)(query + (size_t)(baseRow) * NF);              \
    const float2* q1_ = (const float2*)(query + (size_t)((baseRow) +   stride) * NF); \
    const float2* q2_ = (const float2*)(query + (size_t)((baseRow) + 2*stride) * NF); \
    const float2* q3_ = (const float2*)(query + (size_t)((baseRow) + 3*stride) * NF); \
    A0 = zf2; B0 = zf2; A1 = zf2; B1 = zf2;                                           \
    A2 = zf2; B2 = zf2; A3 = zf2; B3 = zf2;                                           \
    if (j < 13) { A0 = q0_[j];    A1 = q1_[j];    A2 = q2_[j];    A3 = q3_[j]; }      \
    if (j < 12) { B0 = q0_[13+j]; B1 = q1_[13+j]; B2 = q2_[13+j]; B3 = q3_[13+j]; }   \
} while (0)

// Pass 1: fixed-shift softmax-weighted accumulation, 2-deep software pipeline.
// score = sumW - 2 * sum_f w_f / (e^{2 qW x}+1); e_row = exp2(K - 2log2e * rowsum)
// 512 threads = 32 groups of 16 lanes; launch_bounds(512,6) -> ~80 VGPR budget
// so the prefetched chunk (16 regs) can stay in flight during compute.
__global__ __launch_bounds__(512, 6) void attn_pass1(
    const float* __restrict__ query, const float* __restrict__ ql_w,
    const float* __restrict__ qWp, float* __restrict__ ws,
    int T, int totalGroups)
{
    const float qW = qWp[0];
    const int tid  = threadIdx.x;
    const int j    = tid & 15;
    const int gIn  = tid >> 4;
    const int gGlob = blockIdx.x * GRP_PER_BLK + gIn;
    const float2 zf2 = make_float2(0.f, 0.f);

    float wA0 = 0.f, wA1 = 0.f, wB0 = 0.f, wB1 = 0.f;
    if (j < 13) { wA0 = ql_w[2*j];     wA1 = ql_w[2*j+1]; }
    if (j < 12) { wB0 = ql_w[26+2*j];  wB1 = ql_w[27+2*j]; }

    const float sumAbsW = row16_allsum(fabsf(wA0)+fabsf(wA1)+fabsf(wB0)+fabsf(wB1));
    const float sumW    = row16_allsum(wA0 + wA1 + wB0 + wB1);
    const float M0 = (sumAbsW > 80.f) ? (sumAbsW - 80.f) : 0.f;  // overflow guard; 0 here
    const float c2 = 2.f * qW * LOG2E;
    const float K  = (sumW - M0) * LOG2E;
    const float n2l = -2.f * LOG2E;

    float s = 0.f, z0 = 0.f, z1 = 0.f, z2 = 0.f, z3 = 0.f;

    const int stride = totalGroups;
    int row = gGlob;

    float2 cA0,cB0,cA1,cB1,cA2,cB2,cA3,cB3;
    float2 nA0,nB0,nA1,nB1,nA2,nB2,nA3,nB3;

    bool have = (row + 3*stride < T);
    if (have) LOAD4(row, cA0,cB0,cA1,cB1,cA2,cB2,cA3,cB3);

    while (have) {
        const int nrow  = row + 4*stride;
        const bool nhave = (nrow + 3*stride < T);
        const int prow  = nhave ? nrow : row;      // clamped: safe dummy prefetch
        LOAD4(prow, nA0,nB0,nA1,nB1,nA2,nB2,nA3,nB3);

        float p0 = row_partial(cA0, cB0, c2, wA0, wA1, wB0, wB1);
        float p1 = row_partial(cA1, cB1, c2, wA0, wA1, wB0, wB1);
        float p2 = row_partial(cA2, cB2, c2, wA0, wA1, wB0, wB1);
        float p3 = row_partial(cA3, cB3, c2, wA0, wA1, wB0, wB1);
        p0 = row16_allsum(p0);
        p1 = row16_allsum(p1);
        p2 = row16_allsum(p2);
        p3 = row16_allsum(p3);
        float e0 = __builtin_amdgcn_exp2f(fmaf(p0, n2l, K));
        float e1 = __builtin_amdgcn_exp2f(fmaf(p1, n2l, K));
        float e2 = __builtin_amdgcn_exp2f(fmaf(p2, n2l, K));
        float e3 = __builtin_amdgcn_exp2f(fmaf(p3, n2l, K));

        s += (e0 + e1) + (e2 + e3);
        z0 = fmaf(e0, cA0.x, fmaf(e1, cA1.x, fmaf(e2, cA2.x, fmaf(e3, cA3.x, z0))));
        z1 = fmaf(e0, cA0.y, fmaf(e1, cA1.y, fmaf(e2, cA2.y, fmaf(e3, cA3.y, z1))));
        z2 = fmaf(e0, cB0.x, fmaf(e1, cB1.x, fmaf(e2, cB2.x, fmaf(e3, cB3.x, z2))));
        z3 = fmaf(e0, cB0.y, fmaf(e1, cB1.y, fmaf(e2, cB2.y, fmaf(e3, cB3.y, z3))));

        cA0=nA0; cB0=nB0; cA1=nA1; cB1=nB1;
        cA2=nA2; cB2=nB2; cA3=nA3; cB3=nB3;
        row = nrow; have = nhave;
    }
    for (; row < T; row += stride) {
        const float2* q0 = (const float2*)(query + (size_t)row * NF);
        float2 a = zf2, b = zf2;
        if (j < 13) a = q0[j];
        if (j < 12) b = q0[13+j];
        float p = row_partial(a, b, c2, wA0, wA1, wB0, wB1);
        p = row16_allsum(p);
        float e = __builtin_amdgcn_exp2f(fmaf(p, n2l, K));
        s += e;
        z0 = fmaf(e, a.x, z0);
        z1 = fmaf(e, a.y, z1);
        z2 = fmaf(e, b.x, z2);
        z3 = fmaf(e, b.y, z3);
    }

    __shared__ float sz[GRP_PER_BLK][REC];
    if (j < 13) { sz[gIn][2*j]    = z0; sz[gIn][2*j+1]  = z1; }
    if (j < 12) { sz[gIn][26+2*j] = z2; sz[gIn][27+2*j] = z3; }
    if (j == 13) { sz[gIn][50] = s; sz[gIn][51] = 0.f; }
    __syncthreads();

    // per-block record = plain sum over the 32 groups (same shift everywhere)
    if (tid < 51) {
        float acc = 0.f;
        #pragma unroll
        for (int h = 0; h < GRP_PER_BLK; ++h) acc += sz[h][tid];
        ws[(size_t)blockIdx.x * REC + tid] = acc;
    }
}

// Pass 2: plain sum of B records (50 z + s each), divide, store.
__global__ __launch_bounds__(1024) void attn_pass2(
    const float* __restrict__ ws, float* __restrict__ out, int B)
{
    __shared__ float zacc[16][REC];
    const int tid = threadIdx.x;
    const int w = tid >> 6, lane = tid & 63;

    if (lane < 51) {
        float acc = 0.f;
        int b = w;
        for (; b + 112 < B; b += 128) {
            acc += ws[(size_t)(b      ) * REC + lane]
                 + ws[(size_t)(b +  16) * REC + lane]
                 + ws[(size_t)(b +  32) * REC + lane]
                 + ws[(size_t)(b +  48) * REC + lane]
                 + ws[(size_t)(b +  64) * REC + lane]
                 + ws[(size_t)(b +  80) * REC + lane]
                 + ws[(size_t)(b +  96) * REC + lane]
                 + ws[(size_t)(b + 112) * REC + lane];
        }
        for (; b < B; b += 16)
            acc += ws[(size_t)b * REC + lane];
        zacc[w][lane] = acc;
    }
    __syncthreads();
    if (tid < NF) {
        float Z = 0.f, S = 0.f;
        #pragma unroll
        for (int h = 0; h < 16; ++h) { Z += zacc[h][tid]; S += zacc[h][50]; }
        out[tid] = Z / S;
    }
}

extern "C" void kernel_launch(void* const* d_in, const int* in_sizes, int n_in,
                              void* d_out, int out_size, void* d_ws, size_t ws_size,
                              hipStream_t stream) {
    const float* query = (const float*)d_in[0];
    const float* ql_w  = (const float*)d_in[1];
    const float* qW    = (const float*)d_in[2];
    float* out = (float*)d_out;
    float* ws  = (float*)d_ws;

    const int T = in_sizes[0] / NF;

    int B = NBLK;
    size_t need = (size_t)B * REC * sizeof(float);
    if (ws_size < need) {
        B = (int)(ws_size / (REC * sizeof(float)));
        if (B < 1) B = 1;
    }

    const int totalGroups = B * GRP_PER_BLK;
    hipLaunchKernelGGL(attn_pass1, dim3(B), dim3(512), 0, stream,
                       query, ql_w, qW, ws, T, totalGroups);
    hipLaunchKernelGGL(attn_pass2, dim3(1), dim3(1024), 0, stream,
                       ws, out, B);
}